// Round 9
// baseline (824.652 us; speedup 1.0000x reference)
//
#include <hip/hip_runtime.h>
#include <math.h>

#define SDIM 128
#define HID 64
#define DEPTH 4
#define CUTOFF_F 5.0f
#define CHUNK 4096

typedef __attribute__((ext_vector_type(8))) short bf16x8;   // 8 bf16 = 4 VGPRs
typedef __attribute__((ext_vector_type(4))) float f32x4;
typedef float4 __attribute__((aligned(4))) float4_u;        // 4B-aligned float4 load

// fast silu: v_exp + v_rcp
__device__ __forceinline__ float silu_f(float x) {
    float e = __expf(-x);
    return x * __builtin_amdgcn_rcpf(1.0f + e);
}

__device__ __forceinline__ unsigned short f2bf(float x) {
    unsigned int u = __float_as_uint(x);
    unsigned int r = (u + 0x7fffu + ((u >> 16) & 1u)) >> 16;   // RNE
    return (unsigned short)r;
}
__device__ __forceinline__ float bf2f(unsigned short u) {
    return __uint_as_float(((unsigned int)u) << 16);
}

struct f8 { float v[8]; };
__device__ __forceinline__ f8 load8(const float* p) {
    f8 r;
    float4 a = *(const float4*)p;
    float4 b = *(const float4*)(p + 4);
    r.v[0]=a.x; r.v[1]=a.y; r.v[2]=a.z; r.v[3]=a.w;
    r.v[4]=b.x; r.v[5]=b.y; r.v[6]=b.z; r.v[7]=b.w;
    return r;
}
__device__ __forceinline__ bf16x8 pack8(const float* h) {
    bf16x8 o;
#pragma unroll
    for (int j = 0; j < 8; ++j) o[j] = (short)f2bf(h[j]);
    return o;
}
__device__ __forceinline__ void unpack8(bf16x8 b, float* o) {
#pragma unroll
    for (int j = 0; j < 8; ++j)
        o[j] = __uint_as_float(((unsigned int)(unsigned short)b[j]) << 16);
}

// ---------------------------------------------------------------------------
// Index decode + degree histogram.
// ---------------------------------------------------------------------------
__global__ void detect_idx_kernel(const void* ei, int N, int* flag) {
    int lane = threadIdx.x;   // 64 lanes
    const long long* p64 = (const long long*)ei;
    long long v = p64[lane];
    bool ok = (v >= 0 && v < (long long)N);
    unsigned long long m = __ballot(ok);
    if (lane == 0) *flag = (m == ~0ull) ? 1 : 0;
}

__global__ void decode_idx_kernel(const void* ei, int E, int N, const int* flag,
                                  int* __restrict__ srcw, int* __restrict__ dstw,
                                  int* __restrict__ deg_i) {
    int i = blockIdx.x * blockDim.x + threadIdx.x;
    if (i >= 2 * E) return;
    int v;
    if (*flag) v = (int)((const long long*)ei)[i];
    else       v = ((const int*)ei)[i];
    v = min(max(v, 0), N - 1);
    if (i < E) {
        srcw[i] = v;
    } else {
        dstw[i - E] = v;
        atomicAdd(&deg_i[v], 1);
    }
}

// ---------------------------------------------------------------------------
// 3-phase parallel exclusive scan: deg_i -> row_start[0..N]
// ---------------------------------------------------------------------------
__global__ __launch_bounds__(256) void scan1_kernel(const int* __restrict__ deg_i,
                                                    int* __restrict__ part, int N) {
    __shared__ int wsum[4];
    int b = blockIdx.x, t = threadIdx.x;
    int base = b * CHUNK;
    int sum = 0;
    for (int i = t; i < CHUNK; i += 256) {
        int idx = base + i;
        sum += (idx < N) ? deg_i[idx] : 0;
    }
#pragma unroll
    for (int off = 32; off; off >>= 1) sum += __shfl_down(sum, off, 64);
    if ((t & 63) == 0) wsum[t >> 6] = sum;
    __syncthreads();
    if (t == 0) part[b] = wsum[0] + wsum[1] + wsum[2] + wsum[3];
}

__global__ void scan2_kernel(int* __restrict__ part, int* __restrict__ row_start,
                             int B1, int N) {
    int t = threadIdx.x;   // 64 threads
    int v = (t < B1) ? part[t] : 0;
    int incl = v;
#pragma unroll
    for (int off = 1; off < 64; off <<= 1) {
        int x = __shfl_up(incl, off, 64);
        if (t >= off) incl += x;
    }
    if (t < B1) part[t] = incl - v;      // exclusive
    if (t == 63) row_start[N] = incl;    // grand total
}

__global__ __launch_bounds__(256) void scan3_kernel(const int* __restrict__ deg_i,
                                                    const int* __restrict__ part,
                                                    int* __restrict__ row_start, int N) {
    __shared__ int wsum[4];
    __shared__ int carry_s;
    int b = blockIdx.x, t = threadIdx.x;
    int lane = t & 63, w = t >> 6;
    if (t == 0) carry_s = part[b];
    __syncthreads();
    int base0 = b * CHUNK;
    for (int base = base0; base < base0 + CHUNK; base += 256) {
        int i = base + t;
        int v = (i < N) ? deg_i[i] : 0;
        int incl = v;
#pragma unroll
        for (int off = 1; off < 64; off <<= 1) {
            int x = __shfl_up(incl, off, 64);
            if (lane >= off) incl += x;
        }
        if (lane == 63) wsum[w] = incl;
        __syncthreads();
        int wpre = 0;
#pragma unroll
        for (int k = 0; k < 4; ++k) if (k < w) wpre += wsum[k];
        int total = wsum[0] + wsum[1] + wsum[2] + wsum[3];
        int carry = carry_s;
        if (i < N) row_start[i] = carry + wpre + incl - v;
        __syncthreads();
        if (t == 0) carry_s = carry + total;
        __syncthreads();
    }
}

// ---------------------------------------------------------------------------
// Scatter: dst-sorted permutation; one packed 32B record per edge.
// ---------------------------------------------------------------------------
__global__ void scatter_kernel(const int* __restrict__ srcw, const int* __restrict__ dstw,
                               const float* __restrict__ dvec, const float* __restrict__ rvec,
                               const int* __restrict__ row_start, int* __restrict__ cursor,
                               float* __restrict__ rec, int E) {
    int e = blockIdx.x * blockDim.x + threadIdx.x;
    if (e >= E) return;
    int dd = dstw[e];
    int ofs = atomicAdd(&cursor[dd], 1);
    int pos = row_start[dd] + ofs;
    float dv = dvec[e];
    float c = 0.5f * (cosf(3.14159265358979323846f * dv * (1.0f / CUTOFF_F)) + 1.0f);
    c = (dv < CUTOFF_F) ? c : 0.0f;
    float4 r0 = make_float4(__int_as_float(srcw[e]), __int_as_float(dd), dv, c);
    float4 r1 = make_float4(rvec[(size_t)e * 3 + 0], rvec[(size_t)e * 3 + 1],
                            rvec[(size_t)e * 3 + 2], 0.0f);
    *(float4*)(rec + (size_t)pos * 8)     = r0;
    *(float4*)(rec + (size_t)pos * 8 + 4) = r1;
}

// ---------------------------------------------------------------------------
// Weight transpose+cast to bf16 [n][k] for MFMA B-operands.
// ---------------------------------------------------------------------------
__global__ __launch_bounds__(256) void wprep_kernel(
    const float* __restrict__ We1, const float* __restrict__ We2,
    const float* __restrict__ Wv,  const float* __restrict__ Wn1,
    const float* __restrict__ Wn2,
    unsigned short* __restrict__ We1t, unsigned short* __restrict__ We2t,
    unsigned short* __restrict__ Wvt,  unsigned short* __restrict__ Wn1t,
    unsigned short* __restrict__ Wn2t) {
    int l = blockIdx.x, t = threadIdx.x;
    const float* W2 = We2 + (size_t)l * HID * HID;
    unsigned short* T2 = We2t + (size_t)l * HID * HID;
    for (int idx = t; idx < HID * HID; idx += 256) {
        int n = idx >> 6, k = idx & 63;
        T2[n * 64 + k] = f2bf(W2[k * HID + n]);
    }
    const float* Wvl = Wv + (size_t)l * HID * 6;
    unsigned short* Tv = Wvt + (size_t)l * 16 * 64;
    for (int idx = t; idx < 16 * 64; idx += 256) {
        int n = idx >> 6, k = idx & 63;
        Tv[idx] = (n < 6) ? f2bf(Wvl[k * 6 + n]) : (unsigned short)0;
    }
    const float* W1 = We1 + (size_t)l * 257 * 64;
    unsigned short* T1 = We1t + (size_t)l * 128 * 128;
    for (int idx = t; idx < 128 * 128; idx += 256) {
        int n = idx >> 7, k = idx & 127;
        float w = (n < 64) ? W1[(size_t)k * 64 + n] : W1[(size_t)(k + 128) * 64 + (n - 64)];
        T1[n * 128 + k] = f2bf(w);
    }
    const float* Wn1l = Wn1 + (size_t)l * 192 * 64;
    unsigned short* Tn1 = Wn1t + (size_t)l * 64 * 192;
    for (int idx = t; idx < 64 * 192; idx += 256) {
        int n = idx / 192, k = idx - n * 192;
        Tn1[idx] = f2bf(Wn1l[(size_t)k * 64 + n]);
    }
    const float* Wn2l = Wn2 + (size_t)l * 64 * 128;
    unsigned short* Tn2 = Wn2t + (size_t)l * 128 * 64;
    for (int idx = t; idx < 128 * 64; idx += 256) {
        int n = idx >> 6, k = idx & 63;
        Tn2[idx] = f2bf(Wn2l[(size_t)k * 128 + n]);
    }
}

// ---------------------------------------------------------------------------
// node_pre (layer 0 only): [Pa|Pb] = s @ [We1a|We1b] (+be1 on Pa), bf16 out
// ---------------------------------------------------------------------------
__global__ __launch_bounds__(256) void node_pre_kernel(
    const float* __restrict__ s, const unsigned short* __restrict__ We1t,
    const float* __restrict__ be1,
    unsigned short* __restrict__ Pa, unsigned short* __restrict__ Pb, int N)
{
    __shared__ unsigned short sa[64 * 136];
    int t = threadIdx.x;
    int n0 = blockIdx.x * 64;
    for (int idx = t; idx < 64 * 32; idx += 256) {
        int rn = idx >> 5, c4 = (idx & 31) << 2;
        int n = n0 + rn;
        float4 val = make_float4(0.f, 0.f, 0.f, 0.f);
        if (n < N) val = *(const float4*)(s + (size_t)n * SDIM + c4);
        unsigned int p0 = (unsigned int)f2bf(val.x) | ((unsigned int)f2bf(val.y) << 16);
        unsigned int p1 = (unsigned int)f2bf(val.z) | ((unsigned int)f2bf(val.w) << 16);
        *(uint2*)(sa + rn * 136 + c4) = make_uint2(p0, p1);
    }
    __syncthreads();
    int lane = t & 63, w = t >> 6;
    int lm = lane & 15, lq = lane >> 4;
    int m0 = w * 16, rm = m0 + lm;

    bf16x8 af[4];
#pragma unroll
    for (int kc = 0; kc < 4; ++kc)
        af[kc] = *(const bf16x8*)(sa + rm * 136 + kc * 32 + lq * 8);

#pragma unroll
    for (int ct = 0; ct < 8; ++ct) {
        int col = ct * 16 + lm;
        f32x4 acc = {0.f, 0.f, 0.f, 0.f};
#pragma unroll
        for (int kc = 0; kc < 4; ++kc) {
            bf16x8 b = *(const bf16x8*)(We1t + (size_t)col * 128 + kc * 32 + lq * 8);
            acc = __builtin_amdgcn_mfma_f32_16x16x32_bf16(af[kc], b, acc, 0, 0, 0);
        }
        float bias = (ct < 4) ? be1[col] : 0.0f;
#pragma unroll
        for (int g = 0; g < 4; ++g) {
            int n = n0 + m0 + lq * 4 + g;
            if (n < N) {
                if (ct < 4) Pa[(size_t)n * HID + col]        = f2bf(acc[g] + bias);
                else        Pb[(size_t)n * HID + (col - 64)] = f2bf(acc[g]);
            }
        }
    }
}

// ---------------------------------------------------------------------------
// Fused edge kernel (dst-sorted). Aggregation via whole-block segmented
// reduction: interior dst runs -> plain stores (globally exclusive);
// only runs touching block rows 0/63 -> atomics.
// ---------------------------------------------------------------------------
__global__ __launch_bounds__(256) void edge_kernel(
    const float* __restrict__ rec,
    const unsigned short* __restrict__ Pa, const unsigned short* __restrict__ Pb,
    const float* __restrict__ wd,
    const unsigned short* __restrict__ We2t, const float* __restrict__ be2,
    const unsigned short* __restrict__ Wvt, const float* __restrict__ bv,
    const float* __restrict__ v,
    float* __restrict__ agg_s, float* __restrict__ agg_v, int E)
{
    __shared__ unsigned short hb[64 * 72];   // h bf16, stride 72 shorts (144B)
    __shared__ float gl[64 * 8];
    __shared__ float vb[64 * 12];            // v[src] rows (9 used, pad 12)
    __shared__ int   m_src[64], m_dst[64];
    __shared__ float m_d[64], m_C[64];
    __shared__ float m_r[64 * 3];
    int t = threadIdx.x;
    int e0 = blockIdx.x * 64;
    if (t < 64) {
        int e = e0 + t;
        int ec = (e < E) ? e : (E - 1);
        float4 r0 = *(const float4*)(rec + (size_t)ec * 8);
        float4 r1 = *(const float4*)(rec + (size_t)ec * 8 + 4);
        m_src[t] = __float_as_int(r0.x);
        m_dst[t] = __float_as_int(r0.y);
        m_d[t]   = r0.z;
        m_C[t]   = (e < E) ? r0.w : 0.0f;
        m_r[t*3+0] = r1.x; m_r[t*3+1] = r1.y; m_r[t*3+2] = r1.z;
    }
    __syncthreads();

    int lane = t & 63;
    int w    = t >> 6;
    int lm = lane & 15, lq = lane >> 4;
    int m0 = w * 16;
    int rm = m0 + lm;
    int ka = lq * 8;
    int kb = 32 + lq * 8;

    // ---- stage v[src] rows into LDS (3 requests/row) ----
    if (t < 64) {
        const float* vr = v + (size_t)m_src[t] * 9;
        float4_u a = *(const float4_u*)vr;
        float4_u b = *(const float4_u*)(vr + 4);
        float c = vr[8];
        vb[t*12+0]=a.x; vb[t*12+1]=a.y; vb[t*12+2]=a.z; vb[t*12+3]=a.w;
        vb[t*12+4]=b.x; vb[t*12+5]=b.y; vb[t*12+6]=b.z; vb[t*12+7]=b.w;
        vb[t*12+8]=c;
    }
    // ---- prefetch Wv^T fragments (consumed after phase 2) ----
    bf16x8 wv0 = *(const bf16x8*)(Wvt + (size_t)lm * 64 + ka);
    bf16x8 wv1 = *(const bf16x8*)(Wvt + (size_t)lm * 64 + kb);

    // ---- phase 1: h1 in MFMA A-layout, registers only (bf16 gathers) ----
    bf16x8 afr0, afr1;
    {
        int dstr = m_dst[rm], srcr = m_src[rm];
        float dv = m_d[rm];
        const unsigned short* pa = Pa + (size_t)dstr * HID;
        const unsigned short* pb = Pb + (size_t)srcr * HID;
        bf16x8 ba0 = *(const bf16x8*)(pa + ka);
        bf16x8 bb0 = *(const bf16x8*)(pb + ka);
        bf16x8 ba1 = *(const bf16x8*)(pa + kb);
        bf16x8 bb1 = *(const bf16x8*)(pb + kb);
        f8 xw = load8(wd + ka), yw = load8(wd + kb);
        float fa[8], fb[8], h1[8];
        unpack8(ba0, fa); unpack8(bb0, fb);
#pragma unroll
        for (int j = 0; j < 8; ++j) h1[j] = silu_f(fa[j] + fb[j] + dv * xw.v[j]);
        afr0 = pack8(h1);
        unpack8(ba1, fa); unpack8(bb1, fb);
#pragma unroll
        for (int j = 0; j < 8; ++j) h1[j] = silu_f(fa[j] + fb[j] + dv * yw.v[j]);
        afr1 = pack8(h1);
    }

    // ---- phase 2: h = silu(h1@We2+be2)*C via MFMA -> hb bf16 ----
#pragma unroll
    for (int t4 = 0; t4 < 4; ++t4) {
        int col = t4 * 16 + lm;
        bf16x8 b0 = *(const bf16x8*)(We2t + (size_t)col * 64 + ka);
        bf16x8 b1 = *(const bf16x8*)(We2t + (size_t)col * 64 + kb);
        f32x4 a = {0.f, 0.f, 0.f, 0.f};
        a = __builtin_amdgcn_mfma_f32_16x16x32_bf16(afr0, b0, a, 0, 0, 0);
        a = __builtin_amdgcn_mfma_f32_16x16x32_bf16(afr1, b1, a, 0, 0, 0);
        float bias = be2[col];
#pragma unroll
        for (int g = 0; g < 4; ++g) {
            int er = m0 + lq * 4 + g;
            hb[er * 72 + col] = f2bf(silu_f(a[g] + bias) * m_C[er]);
        }
    }
    __syncthreads();

    // ---- gates = h @ Wv + bv via MFMA (A-frags straight from bf16 LDS) ----
    {
        bf16x8 ga0 = *(const bf16x8*)(hb + rm * 72 + ka);
        bf16x8 ga1 = *(const bf16x8*)(hb + rm * 72 + kb);
        f32x4 ga = {0.f, 0.f, 0.f, 0.f};
        ga = __builtin_amdgcn_mfma_f32_16x16x32_bf16(ga0, wv0, ga, 0, 0, 0);
        ga = __builtin_amdgcn_mfma_f32_16x16x32_bf16(ga1, wv1, ga, 0, 0, 0);
        if (lm < 6) {
            float bias = bv[lm];
#pragma unroll
            for (int g = 0; g < 4; ++g) {
                int er = m0 + lq * 4 + g;
                gl[er * 8 + lm] = ga[g] + bias;
            }
        }
    }
    __syncthreads();   // gl ready; hb stable

    // ---- agg_s: wave 0, lane = column, serial 64-row segmented reduction.
    //      Interior runs (start>0, end<63) are block-exclusive -> plain store.
    if (t < 64) {
        int c = t;
        float acc = 0.f;
        int cur = m_dst[0];
        int run_start = 0;
#pragma unroll 4
        for (int r = 0; r < 64; ++r) {
            int dr = m_dst[r];
            if (dr != cur) {
                float* dst = &agg_s[(size_t)cur * HID + c];
                if (run_start == 0) atomicAdd(dst, acc);
                else                *dst = acc;          // exclusive to this block
                acc = 0.f; cur = dr; run_start = r;
            }
            acc += bf2f(hb[r * 72 + c]);
        }
        atomicAdd(&agg_s[(size_t)cur * HID + c], acc);   // touches row 63
    }
    // ---- agg_v: wave 1 lanes 0..8, col c, serial 64-row segmented reduction ----
    else if (t >= 64 && t < 73) {
        int c = t - 64;
        int i = c / 3, j = c - i * 3;
        float acc = 0.f;
        int cur = m_dst[0];
        int run_start = 0;
#pragma unroll 4
        for (int r = 0; r < 64; ++r) {
            int dr = m_dst[r];
            if (dr != cur) {
                float* dst = &agg_v[(size_t)cur * 9 + c];
                if (run_start == 0) atomicAdd(dst, acc);
                else                *dst = acc;
                acc = 0.f; cur = dr; run_start = r;
            }
            if (e0 + r < E) {
                acc += vb[r * 12 + c] * gl[r * 8 + j]
                     + m_r[r * 3 + i] * gl[r * 8 + 3 + j];
            }
        }
        atomicAdd(&agg_v[(size_t)cur * 9 + c], acc);
    }
}

// ---------------------------------------------------------------------------
// Fused node kernel: u = silu([s,agg_s]@Wn1+bn1); s += u@Wn2+bn2;
// v += agg_v/deg; then (do_pre) [Pa|Pb] = s_new @ We1(l+1) (bf16 out).
// Zeroes agg_s/agg_v for the next layer (zero-after-read).
// ---------------------------------------------------------------------------
__global__ __launch_bounds__(256) void node_fused_kernel(
    float* __restrict__ s, float* __restrict__ vout,
    float* __restrict__ agg_s, float* __restrict__ agg_v,
    const int* __restrict__ row_start,
    const unsigned short* __restrict__ Wn1t, const float* __restrict__ bn1,
    const unsigned short* __restrict__ Wn2t, const float* __restrict__ bn2,
    const unsigned short* __restrict__ We1tn, const float* __restrict__ be1n,
    unsigned short* __restrict__ Pa, unsigned short* __restrict__ Pb,
    int N, int do_pre)
{
    __shared__ unsigned short xa[64 * 200];  // phase A: [s|agg_s]; phase B alias: s_new (stride 136)
    __shared__ unsigned short ub[64 * 72];
    int t = threadIdx.x;
    int n0 = blockIdx.x * 64;
    for (int idx = t; idx < 64 * 32; idx += 256) {
        int rn = idx >> 5, c4 = (idx & 31) << 2;
        int n = n0 + rn;
        float4 val = make_float4(0.f, 0.f, 0.f, 0.f);
        if (n < N) val = *(const float4*)(s + (size_t)n * SDIM + c4);
        unsigned int p0 = (unsigned int)f2bf(val.x) | ((unsigned int)f2bf(val.y) << 16);
        unsigned int p1 = (unsigned int)f2bf(val.z) | ((unsigned int)f2bf(val.w) << 16);
        *(uint2*)(xa + rn * 200 + c4) = make_uint2(p0, p1);
    }
    for (int idx = t; idx < 64 * 16; idx += 256) {
        int rn = idx >> 4, c4 = (idx & 15) << 2;
        int n = n0 + rn;
        float4 val = make_float4(0.f, 0.f, 0.f, 0.f);
        if (n < N) {
            float* ap = agg_s + (size_t)n * HID + c4;
            val = *(const float4*)ap;
            *(float4*)ap = make_float4(0.f, 0.f, 0.f, 0.f);   // zero for next layer
        }
        unsigned int p0 = (unsigned int)f2bf(val.x) | ((unsigned int)f2bf(val.y) << 16);
        unsigned int p1 = (unsigned int)f2bf(val.z) | ((unsigned int)f2bf(val.w) << 16);
        *(uint2*)(xa + rn * 200 + 128 + c4) = make_uint2(p0, p1);
    }
    __syncthreads();

    int lane = t & 63, w = t >> 6;
    int lm = lane & 15, lq = lane >> 4;
    int m0 = w * 16, rm = m0 + lm;

    // ---- GEMM1: u = silu(x @ Wn1 + bn1) ----
    bf16x8 af[6];
#pragma unroll
    for (int kc = 0; kc < 6; ++kc)
        af[kc] = *(const bf16x8*)(xa + rm * 200 + kc * 32 + lq * 8);

#pragma unroll
    for (int ct = 0; ct < 4; ++ct) {
        int col = ct * 16 + lm;
        f32x4 acc = {0.f, 0.f, 0.f, 0.f};
#pragma unroll
        for (int kc = 0; kc < 6; ++kc) {
            bf16x8 b = *(const bf16x8*)(Wn1t + (size_t)col * 192 + kc * 32 + lq * 8);
            acc = __builtin_amdgcn_mfma_f32_16x16x32_bf16(af[kc], b, acc, 0, 0, 0);
        }
        float bias = bn1[col];
#pragma unroll
        for (int g = 0; g < 4; ++g) {
            int er = m0 + lq * 4 + g;
            ub[er * 72 + col] = f2bf(silu_f(acc[g] + bias));
        }
    }
    __syncthreads();   // ub ready; xa reads done -> reusable

    // ---- GEMM2: s_new = s + u @ Wn2 + bn2 ; stash s_new bf16 in LDS ----
    unsigned short* sa = xa;   // alias (stride 136)
    bf16x8 uf[2];
#pragma unroll
    for (int kc = 0; kc < 2; ++kc)
        uf[kc] = *(const bf16x8*)(ub + rm * 72 + kc * 32 + lq * 8);

#pragma unroll
    for (int ct = 0; ct < 8; ++ct) {
        int col = ct * 16 + lm;
        f32x4 acc = {0.f, 0.f, 0.f, 0.f};
#pragma unroll
        for (int kc = 0; kc < 2; ++kc) {
            bf16x8 b = *(const bf16x8*)(Wn2t + (size_t)col * 64 + kc * 32 + lq * 8);
            acc = __builtin_amdgcn_mfma_f32_16x16x32_bf16(uf[kc], b, acc, 0, 0, 0);
        }
        float bias = bn2[col];
#pragma unroll
        for (int g = 0; g < 4; ++g) {
            int er = m0 + lq * 4 + g;
            int n = n0 + er;
            if (n < N) {
                float* sp = s + (size_t)n * SDIM + col;
                float sv = *sp + acc[g] + bias;
                *sp = sv;
                sa[er * 136 + col] = f2bf(sv);
            } else {
                sa[er * 136 + col] = 0;
            }
        }
    }
    __syncthreads();   // sa ready

    // ---- pre-GEMM for next layer: [Pa|Pb] = s_new @ We1(l+1) (bf16 out) ----
    if (do_pre) {
        bf16x8 pf[4];
#pragma unroll
        for (int kc = 0; kc < 4; ++kc)
            pf[kc] = *(const bf16x8*)(sa + rm * 136 + kc * 32 + lq * 8);

#pragma unroll
        for (int ct = 0; ct < 8; ++ct) {
            int col = ct * 16 + lm;
            f32x4 acc = {0.f, 0.f, 0.f, 0.f};
#pragma unroll
            for (int kc = 0; kc < 4; ++kc) {
                bf16x8 b = *(const bf16x8*)(We1tn + (size_t)col * 128 + kc * 32 + lq * 8);
                acc = __builtin_amdgcn_mfma_f32_16x16x32_bf16(pf[kc], b, acc, 0, 0, 0);
            }
            float bias = (ct < 4) ? be1n[col] : 0.0f;
#pragma unroll
            for (int g = 0; g < 4; ++g) {
                int n = n0 + m0 + lq * 4 + g;
                if (n < N) {
                    if (ct < 4) Pa[(size_t)n * HID + col]        = f2bf(acc[g] + bias);
                    else        Pb[(size_t)n * HID + (col - 64)] = f2bf(acc[g]);
                }
            }
        }
    }

    // ---- v += agg_v / max(deg,1) ; zero agg_v for next layer ----
    for (int idx = t; idx < 64 * 9; idx += 256) {
        int rn = idx / 9, c = idx - rn * 9;
        int n2 = n0 + rn;
        if (n2 < N) {
            float av = agg_v[(size_t)n2 * 9 + c];
            agg_v[(size_t)n2 * 9 + c] = 0.f;
            float dg = fmaxf((float)(row_start[n2 + 1] - row_start[n2]), 1.0f);
            vout[(size_t)n2 * 9 + c] += av / dg;
        }
    }
}

extern "C" void kernel_launch(void* const* d_in, const int* in_sizes, int n_in,
                              void* d_out, int out_size, void* d_ws, size_t ws_size,
                              hipStream_t stream)
{
    const float* s_in  = (const float*)d_in[0];
    const float* v_in  = (const float*)d_in[1];
    const void*  ei    = d_in[2];
    const float* d_vec = (const float*)d_in[3];
    const float* r_vec = (const float*)d_in[4];
    const float* We1 = (const float*)d_in[6];
    const float* be1 = (const float*)d_in[7];
    const float* We2 = (const float*)d_in[8];
    const float* be2 = (const float*)d_in[9];
    const float* Wn1 = (const float*)d_in[10];
    const float* bn1 = (const float*)d_in[11];
    const float* Wn2 = (const float*)d_in[12];
    const float* bn2 = (const float*)d_in[13];
    const float* Wv  = (const float*)d_in[14];
    const float* bv  = (const float*)d_in[15];

    int N = in_sizes[0] / SDIM;
    int E = in_sizes[3];

    float* out_s = (float*)d_out;
    float* out_v = out_s + (size_t)N * SDIM;

    // ------ workspace layout (32B-aligned blocks) ------
    char* wp = (char*)d_ws;
    auto alloc = [&wp](size_t bytes) -> char* {
        char* p = wp;
        wp += (bytes + 31) & ~(size_t)31;
        return p;
    };
    float* rec       = (float*)alloc((size_t)E * 8 * 4);
    unsigned short* Pa = (unsigned short*)alloc((size_t)N * HID * 2);
    unsigned short* Pb = (unsigned short*)alloc((size_t)N * HID * 2);
    float* agg_s     = (float*)alloc((size_t)N * HID * 4);   // contiguous with agg_v
    float* agg_v     = (float*)alloc((size_t)N * 9 * 4);
    int*   deg_i     = (int*)alloc((size_t)N * 4);           // contiguous with cursor
    int*   cursor    = (int*)alloc((size_t)N * 4);
    int*   row_start = (int*)alloc((size_t)(N + 1) * 4);
    int*   part      = (int*)alloc(64 * 4);
    int*   flag      = (int*)alloc(16);
    int*   srcw      = (int*)alloc((size_t)E * 4);
    int*   dstw      = (int*)alloc((size_t)E * 4);
    unsigned short* We2t = (unsigned short*)alloc((size_t)DEPTH * HID * HID * 2);
    unsigned short* Wvt  = (unsigned short*)alloc((size_t)DEPTH * 16 * 64 * 2);
    unsigned short* We1t = (unsigned short*)alloc((size_t)DEPTH * 128 * 128 * 2);
    unsigned short* Wn1t = (unsigned short*)alloc((size_t)DEPTH * 64 * 192 * 2);
    unsigned short* Wn2t = (unsigned short*)alloc((size_t)DEPTH * 128 * 64 * 2);

    hipMemcpyAsync(out_s, s_in, (size_t)N * SDIM * sizeof(float),
                   hipMemcpyDeviceToDevice, stream);
    hipMemcpyAsync(out_v, v_in, (size_t)N * 9 * sizeof(float),
                   hipMemcpyDeviceToDevice, stream);

    // ------ one-time prep ------
    detect_idx_kernel<<<1, 64, 0, stream>>>(ei, N, flag);
    hipMemsetAsync(deg_i, 0, (size_t)N * 2 * sizeof(int), stream);    // deg_i + cursor
    hipMemsetAsync(agg_s, 0, (size_t)N * (HID + 9) * sizeof(float), stream);
    decode_idx_kernel<<<(2 * E + 255) / 256, 256, 0, stream>>>(ei, E, N, flag,
                                                               srcw, dstw, deg_i);
    int B1 = (N + CHUNK - 1) / CHUNK;
    scan1_kernel<<<B1, 256, 0, stream>>>(deg_i, part, N);
    scan2_kernel<<<1, 64, 0, stream>>>(part, row_start, B1, N);
    scan3_kernel<<<B1, 256, 0, stream>>>(deg_i, part, row_start, N);
    scatter_kernel<<<(E + 255) / 256, 256, 0, stream>>>(srcw, dstw, d_vec, r_vec,
                                                        row_start, cursor, rec, E);
    wprep_kernel<<<DEPTH, 256, 0, stream>>>(We1, We2, Wv, Wn1, Wn2,
                                            We1t, We2t, Wvt, Wn1t, Wn2t);

    int nb_n = (N + 63) / 64;
    int nb_e = (E + 63) / 64;
    node_pre_kernel<<<nb_n, 256, 0, stream>>>(out_s, We1t, be1, Pa, Pb, N);
    for (int l = 0; l < DEPTH; ++l) {
        int ln = (l + 1 < DEPTH) ? (l + 1) : 0;
        const float* We1_l = We1 + (size_t)l * 257 * 64;
        const float* be2_l = be2 + (size_t)l * 64;
        const float* bn1_l = bn1 + (size_t)l * 64;
        const float* bn2_l = bn2 + (size_t)l * 128;
        const float* bv_l  = bv  + (size_t)l * 6;
        const float* be1_n = be1 + (size_t)ln * 64;
        const unsigned short* We2t_l = We2t + (size_t)l * HID * HID;
        const unsigned short* Wvt_l  = Wvt  + (size_t)l * 16 * 64;
        const unsigned short* Wn1t_l = Wn1t + (size_t)l * 64 * 192;
        const unsigned short* Wn2t_l = Wn2t + (size_t)l * 128 * 64;
        const unsigned short* We1t_n = We1t + (size_t)ln * 128 * 128;

        edge_kernel<<<nb_e, 256, 0, stream>>>(rec, Pa, Pb,
                                              We1_l + 256 * 64,
                                              We2t_l, be2_l, Wvt_l, bv_l,
                                              out_v, agg_s, agg_v, E);
        node_fused_kernel<<<nb_n, 256, 0, stream>>>(out_s, out_v, agg_s, agg_v,
                                                    row_start,
                                                    Wn1t_l, bn1_l, Wn2t_l, bn2_l,
                                                    We1t_n, be1_n, Pa, Pb,
                                                    N, (l + 1 < DEPTH) ? 1 : 0);
    }
}